// Round 6
// baseline (421.766 us; speedup 1.0000x reference)
//
#include <hip/hip_runtime.h>

// ChineseCLIP vision attention, MI355X bf16-MFMA pipeline. Round 6:
//  - qkv: R4's BK=32 m97 K-loop (BK=64 regressed occupancy; reverted).
//  - attn: 512-thread blocks (8 waves) per bh, K+V staged in 68KB LDS
//    (minimal 53MB global traffic) -> 16 waves/CU for latency hiding.
//    exp2-domain softmax (log2e/8 folded into Q scale), Q prefetch.
//  - o_gemm: 64x128 tiles, grid 1032 (was grid-starved at 520 blocks).
// B=32, T=257, D=1024, H=16, HD=64.

#define B_   32
#define T_   257
#define TP   272
#define H_   16
#define HD_  64
#define D_   1024
#define NTOK 8224
#define BH_  512
#define FRAG_PER_BH 17408   // TP*HD elements per (b,h) in frag-major arrays

typedef __bf16 bf16;
typedef __bf16 bf16x4 __attribute__((ext_vector_type(4)));
typedef __bf16 bf16x8 __attribute__((ext_vector_type(8)));
typedef short  s16x4  __attribute__((ext_vector_type(4)));
typedef short  s16x8  __attribute__((ext_vector_type(8)));
typedef float  floatx4 __attribute__((ext_vector_type(4)));

static constexpr size_t SZ_XB   = (size_t)NTOK * D_ * 2;
static constexpr size_t SZ_WQKV = (size_t)3 * D_ * D_ * 2;
static constexpr size_t SZ_W    = (size_t)D_ * D_ * 2;
static constexpr size_t SZ_QK   = (size_t)BH_ * FRAG_PER_BH * 2;

static constexpr size_t OFF_XB   = 0;
static constexpr size_t OFF_WQKV = OFF_XB + SZ_XB;
static constexpr size_t OFF_WO   = OFF_WQKV + SZ_WQKV;
static constexpr size_t OFF_Q    = OFF_WO + SZ_W;
static constexpr size_t OFF_K    = OFF_Q + SZ_QK;
static constexpr size_t OFF_V    = OFF_K + SZ_QK;
static constexpr size_t OFF_CTX  = OFF_V + SZ_QK;

// scale for Q: (1/8) * log2(e) so softmax runs in exp2 domain
#define QSCALE 0.18033688011112042f

#define GLD16(gp, lp)                                                        \
  __builtin_amdgcn_global_load_lds(                                          \
      (const __attribute__((address_space(1))) void*)(gp),                   \
      (__attribute__((address_space(3))) void*)(lp), 16, 0, 0)

// ---------------- fp32 -> bf16 casts ----------------
__global__ void cast_bf16_kernel(const float* __restrict__ src,
                                 bf16* __restrict__ dst, int n4) {
  int i = blockIdx.x * blockDim.x + threadIdx.x;
  int stride = gridDim.x * blockDim.x;
  for (int idx = i; idx < n4; idx += stride) {
    float4 v = reinterpret_cast<const float4*>(src)[idx];
    bf16x4 o;
    o[0] = (bf16)v.x; o[1] = (bf16)v.y; o[2] = (bf16)v.z; o[3] = (bf16)v.w;
    reinterpret_cast<bf16x4*>(dst)[idx] = o;
  }
}

__global__ void cast4_kernel(const float* __restrict__ s0, const float* __restrict__ s1,
                             const float* __restrict__ s2, const float* __restrict__ s3,
                             bf16* __restrict__ d0, bf16* __restrict__ d1,
                             bf16* __restrict__ d2, bf16* __restrict__ d3, int n4) {
  const float* s = (blockIdx.y == 0) ? s0 : (blockIdx.y == 1) ? s1
                   : (blockIdx.y == 2) ? s2 : s3;
  bf16* d = (blockIdx.y == 0) ? d0 : (blockIdx.y == 1) ? d1
            : (blockIdx.y == 2) ? d2 : d3;
  int i = blockIdx.x * blockDim.x + threadIdx.x;
  int stride = gridDim.x * blockDim.x;
  for (int idx = i; idx < n4; idx += stride) {
    float4 v = reinterpret_cast<const float4*>(s)[idx];
    bf16x4 o;
    o[0] = (bf16)v.x; o[1] = (bf16)v.y; o[2] = (bf16)v.z; o[3] = (bf16)v.w;
    reinterpret_cast<bf16x4*>(d)[idx] = o;
  }
}

// Frag-major layouts (element offsets within one bh's 17408 elems):
// Q/K (A/B-op of 16x16x32): [kt(17)][dc(8)][ki(16)][8]  (t=kt*16+ki, d=dc*8+e)
// V   (A-op of 16x16x16, dt-paired): [kt(17)][p(2)][q2(4)][d16(16)][dp(2)][ki(4)]
//     t = kt*16 + q2*4 + ki, d = p*32 + dp*16 + d16.

// ---------------- fused QKV GEMM (R4 BK=32 m97 structure) ----------------
// grid 1560; swizzle: XCD x owns n-tiles {3x..3x+2}; mbase = linear/24.
__global__ __launch_bounds__(256) void qkv_gemm(
    const bf16* __restrict__ xb, const bf16* __restrict__ wqkv,
    const float* __restrict__ bq, const float* __restrict__ bk,
    const float* __restrict__ bv,
    bf16* __restrict__ Qf, bf16* __restrict__ Kf, bf16* __restrict__ Vf) {
  __shared__ bf16 smem[9216];          // K-loop: Ash(4096)+Bsh(4096); epi: 128x72
  bf16* Ash = smem;
  bf16* Bsh = smem + 4096;

  const int linear = blockIdx.x;
  const int nbg = ((linear & 7) * 3 + ((linear >> 3) % 3)) * 128;
  const int mbase = (linear / 24) * 128;
  const int tid = threadIdx.x;
  const int lane = tid & 63;
  const int w = tid >> 6;
  const int wr = w >> 1, wc = w & 1;
  const int n15 = lane & 15, quad = lane >> 4;

  const int lrow = lane >> 2;
  const int lseg = (lane & 3) * 8;

  floatx4 acc[4][4] = {};

  for (int k0 = 0; k0 < D_; k0 += 32) {
#pragma unroll
    for (int c = 0; c < 2; c++) {
      int r0 = w * 32 + c * 16;
      int row = r0 + lrow;
      int gm = mbase + row; if (gm > NTOK - 1) gm = NTOK - 1;
      GLD16(xb + (size_t)gm * D_ + k0 + lseg, Ash + r0 * 32);
      GLD16(wqkv + (size_t)(nbg + row) * D_ + k0 + lseg, Bsh + r0 * 32);
    }
    __syncthreads();
    bf16x8 af[4], bfr[4];
#pragma unroll
    for (int i = 0; i < 4; i++) {
      af[i]  = *reinterpret_cast<const bf16x8*>(Ash + (wr * 64 + i * 16 + n15) * 32 + quad * 8);
      bfr[i] = *reinterpret_cast<const bf16x8*>(Bsh + (wc * 64 + i * 16 + n15) * 32 + quad * 8);
    }
#pragma unroll
    for (int i = 0; i < 4; i++)
#pragma unroll
      for (int j = 0; j < 4; j++)
        acc[i][j] = __builtin_amdgcn_mfma_f32_16x16x32_bf16(af[i], bfr[j], acc[i][j], 0, 0, 0);
    __syncthreads();
  }

  // ---- epilogue: LDS transpose + coalesced frag-major stores ----
  const int z = nbg >> 10;
  bf16* zdst = (z == 0) ? Qf : (z == 1) ? Kf : Vf;
  const float scale = (z == 0) ? QSCALE : 1.0f;
  const float* bias = (z == 0) ? bq : (z == 1) ? bk : bv;
  const int zoff = nbg & 1023;

  const int bA = mbase / T_;
  const int tA = mbase - bA * T_;
  const int tEndA = (tA + 128 < T_) ? tA + 128 : T_;
  const int tgA0 = tA >> 4;
  const int nA = ((tEndA - 1) >> 4) - tgA0 + 1;
  int nU = nA, tEndB = 0;
  if (tA + 128 > T_ && bA + 1 < B_) {
    tEndB = tA + 128 - T_;
    nU += ((tEndB - 1) >> 4) + 1;
  }

  for (int half = 0; half < 2; half++) {
    if (wc == half) {
#pragma unroll
      for (int i = 0; i < 4; i++)
#pragma unroll
        for (int j = 0; j < 4; j++) {
          int colL = j * 16 + n15;
          float bval = bias[zoff + half * 64 + colL];
#pragma unroll
          for (int r = 0; r < 4; r++) {
            int rowL = wr * 64 + i * 16 + quad * 4 + r;
            smem[rowL * 72 + colL] = (bf16)((acc[i][j][r] + bval) * scale);
          }
        }
    }
    __syncthreads();
    const int h = (zoff >> 6) + half;
    for (int u = w; u < nU; u += 4) {
      int b, tg, tlo, thi;
      if (u < nA) {
        b = bA; tg = tgA0 + u;
        tlo = (tA > tg * 16) ? tA : tg * 16;
        int te = tg * 16 + 16; thi = (te < tEndA) ? te : tEndA;
      } else {
        b = bA + 1; tg = u - nA;
        tlo = tg * 16;
        int te = tg * 16 + 16; thi = (te < tEndB) ? te : tEndB;
      }
      bf16* gb = zdst + (size_t)(b * H_ + h) * FRAG_PER_BH + tg * 1024;
      if (z != 2) {
        int ki = lane & 15, dc = lane >> 4;
        int t = tg * 16 + ki;
        if (t >= tlo && t < thi) {
          int rowL = b * T_ + t - mbase;
          bf16x8 v0 = *reinterpret_cast<const bf16x8*>(smem + rowL * 72 + dc * 8);
          bf16x8 v1 = *reinterpret_cast<const bf16x8*>(smem + rowL * 72 + 32 + dc * 8);
          *reinterpret_cast<bf16x8*>(gb + dc * 128 + ki * 8) = v0;
          *reinterpret_cast<bf16x8*>(gb + 512 + dc * 128 + ki * 8) = v1;
        }
      } else {
        int q2 = (lane >> 4) & 3, d16 = lane & 15;
        int tb = tg * 16 + q2 * 4;
        bool full = (tb >= tlo) && (tb + 3 < thi);
#pragma unroll
        for (int p = 0; p < 2; p++) {
          bf16x8 vv;
#pragma unroll
          for (int dp = 0; dp < 2; dp++)
#pragma unroll
            for (int ki = 0; ki < 4; ki++) {
              int t = tb + ki;
              int rr = (b * T_ + t - mbase) & 127;   // safe for masked elems
              vv[dp * 4 + ki] = smem[rr * 72 + p * 32 + dp * 16 + d16];
            }
          bf16* cp = gb + (p * 4 + q2) * 128 + d16 * 8;
          if (full) {
            *reinterpret_cast<bf16x8*>(cp) = vv;
          } else {
#pragma unroll
            for (int dp = 0; dp < 2; dp++)
#pragma unroll
              for (int ki = 0; ki < 4; ki++) {
                int t = tb + ki;
                if (t >= tlo && t < thi) cp[dp * 4 + ki] = vv[dp * 4 + ki];
              }
          }
        }
      }
    }
    __syncthreads();
  }
}

// ---------------- fused attention (8 waves/block, K+V LDS) ----------------
// grid = 512 (one block per bh), 512 threads; wave w handles qt w, w+8, (16).
__global__ __launch_bounds__(512, 4) void attn_kernel(
    const bf16* __restrict__ Qf, const bf16* __restrict__ Kf,
    const bf16* __restrict__ Vf, bf16* __restrict__ ctx) {
  __shared__ bf16 smem[34816];   // K (17408) then V (17408) = 68 KB

  const int bh = blockIdx.x;
  const int tid = threadIdx.x;
  const int lane = tid & 63, w = tid >> 6;   // w in 0..7
  const int n15 = lane & 15, quad = lane >> 4;
  const int b = bh >> 4, h = bh & 15;

  const bf16* Qb = Qf + (size_t)bh * FRAG_PER_BH;
  const bf16* Kb = Kf + (size_t)bh * FRAG_PER_BH;
  const bf16* Vb = Vf + (size_t)bh * FRAG_PER_BH;

  // stage K and V: 68 chunks of 1KB over 8 waves
  for (int c = w; c < 68; c += 8) {
    const bf16* src = (c < 34) ? (Kb + c * 512) : (Vb + (c - 34) * 512);
    GLD16(src + lane * 8, smem + c * 512);
  }
  __syncthreads();
  const bf16* Ksh = smem;
  const bf16* Vsh = smem + 17408;

  const int fo = quad * 128 + n15 * 8;

  bf16x8 cq0 = *reinterpret_cast<const bf16x8*>(Qb + w * 1024 + fo);
  bf16x8 cq1 = *reinterpret_cast<const bf16x8*>(Qb + w * 1024 + 512 + fo);

  for (int qt = w; qt < 17; qt += 8) {
    const int nqt = qt + 8;
    bf16x8 nq0 = {}, nq1 = {};
    if (nqt < 17) {
      nq0 = *reinterpret_cast<const bf16x8*>(Qb + nqt * 1024 + fo);
      nq1 = *reinterpret_cast<const bf16x8*>(Qb + nqt * 1024 + 512 + fo);
    }

    floatx4 s[17];
#pragma unroll
    for (int kt = 0; kt < 17; kt++) {
      bf16x8 ka0 = *reinterpret_cast<const bf16x8*>(Ksh + kt * 1024 + fo);
      bf16x8 ka1 = *reinterpret_cast<const bf16x8*>(Ksh + kt * 1024 + 512 + fo);
      floatx4 c = {};
      c = __builtin_amdgcn_mfma_f32_16x16x32_bf16(ka0, cq0, c, 0, 0, 0);
      c = __builtin_amdgcn_mfma_f32_16x16x32_bf16(ka1, cq1, c, 0, 0, 0);
      s[kt] = c;
    }
    // keys 257..271 invalid: tile 16 holds keys 256+quad*4+r; only 256 valid
    s[16][1] = -1e30f; s[16][2] = -1e30f; s[16][3] = -1e30f;
    if (quad != 0) s[16][0] = -1e30f;

    float m0 = -1e30f;
#pragma unroll
    for (int kt = 0; kt < 17; kt++)
#pragma unroll
      for (int r = 0; r < 4; r++) m0 = fmaxf(m0, s[kt][r]);
    m0 = fmaxf(m0, __shfl_xor(m0, 16));
    m0 = fmaxf(m0, __shfl_xor(m0, 32));

    float sum = 0.f;
    s16x4 pb[17];
#pragma unroll
    for (int kt = 0; kt < 17; kt++) {
      bf16x4 ph;
#pragma unroll
      for (int r = 0; r < 4; r++) {
        float p = exp2f(s[kt][r] - m0);   // scores pre-scaled by log2(e)/8
        sum += p;
        ph[r] = (bf16)p;
      }
      pb[kt] = __builtin_bit_cast(s16x4, ph);
    }
    sum += __shfl_xor(sum, 16);
    sum += __shfl_xor(sum, 32);

    floatx4 o[4] = {};
#pragma unroll
    for (int kt = 0; kt < 17; kt++) {
#pragma unroll
      for (int p = 0; p < 2; p++) {
        bf16x8 vv = *reinterpret_cast<const bf16x8*>(
            Vsh + ((kt * 2 + p) * 4 + quad) * 128 + n15 * 8);
        s16x8 v16 = __builtin_bit_cast(s16x8, vv);
        s16x4 vlo = __builtin_shufflevector(v16, v16, 0, 1, 2, 3);
        s16x4 vhi = __builtin_shufflevector(v16, v16, 4, 5, 6, 7);
        o[p * 2]     = __builtin_amdgcn_mfma_f32_16x16x16bf16_1k(vlo, pb[kt], o[p * 2], 0, 0, 0);
        o[p * 2 + 1] = __builtin_amdgcn_mfma_f32_16x16x16bf16_1k(vhi, pb[kt], o[p * 2 + 1], 0, 0, 0);
      }
    }

    int q = qt * 16 + n15;
    if (q < T_) {
      float inv = 1.0f / sum;
      size_t ob = ((size_t)(b * T_ + q)) * D_ + h * 64 + quad * 4;
#pragma unroll
      for (int dt = 0; dt < 4; dt++) {
        bf16x4 ov;
#pragma unroll
        for (int r = 0; r < 4; r++) ov[r] = (bf16)(o[dt][r] * inv);
        *reinterpret_cast<bf16x4*>(ctx + ob + dt * 16) = ov;
      }
    }
    cq0 = nq0; cq1 = nq1;
  }
}

// ---------------- output projection GEMM (64x128 tile, fp32 out) ----------------
// grid = 1032 = 129 m-tiles x 8 n-tiles (n fastest for ctx A-tile reuse).
__global__ __launch_bounds__(256) void o_gemm(
    const bf16* __restrict__ ctx, const bf16* __restrict__ wo,
    const float* __restrict__ bo, float* __restrict__ out) {
  __shared__ bf16 Ash[64 * 32];
  __shared__ bf16 Bsh[128 * 32];

  const int linear = blockIdx.x;
  const int nbase = (linear & 7) * 128;
  const int mbase = (linear >> 3) * 64;
  const int tid = threadIdx.x;
  const int lane = tid & 63;
  const int w = tid >> 6;
  const int wr = w >> 1, wc = w & 1;   // wave tile: 32(m) x 64(n)
  const int n15 = lane & 15, quad = lane >> 4;

  const int lrow = lane >> 2;
  const int lseg = (lane & 3) * 8;

  floatx4 acc[2][4] = {};

  for (int k0 = 0; k0 < D_; k0 += 32) {
    {
      int r0 = w * 16;
      int gm = mbase + r0 + lrow; if (gm > NTOK - 1) gm = NTOK - 1;
      GLD16(ctx + (size_t)gm * D_ + k0 + lseg, Ash + r0 * 32);
    }
#pragma unroll
    for (int c = 0; c < 2; c++) {
      int r0 = w * 32 + c * 16;
      GLD16(wo + (size_t)(nbase + r0 + lrow) * D_ + k0 + lseg, Bsh + r0 * 32);
    }
    __syncthreads();
    bf16x8 af[2], bfr[4];
#pragma unroll
    for (int i = 0; i < 2; i++)
      af[i] = *reinterpret_cast<const bf16x8*>(Ash + (wr * 32 + i * 16 + n15) * 32 + quad * 8);
#pragma unroll
    for (int j = 0; j < 4; j++)
      bfr[j] = *reinterpret_cast<const bf16x8*>(Bsh + (wc * 64 + j * 16 + n15) * 32 + quad * 8);
#pragma unroll
    for (int i = 0; i < 2; i++)
#pragma unroll
      for (int j = 0; j < 4; j++)
        acc[i][j] = __builtin_amdgcn_mfma_f32_16x16x32_bf16(af[i], bfr[j], acc[i][j], 0, 0, 0);
    __syncthreads();
  }

#pragma unroll
  for (int i = 0; i < 2; i++) {
    int rowb = mbase + wr * 32 + i * 16 + quad * 4;
#pragma unroll
    for (int j = 0; j < 4; j++) {
      int col = nbase + wc * 64 + j * 16 + n15;
      float bval = bo[col];
#pragma unroll
      for (int r = 0; r < 4; r++) {
        int m = rowb + r;
        if (m < NTOK) out[(size_t)m * D_ + col] = acc[i][j][r] + bval;
      }
    }
  }
}

extern "C" void kernel_launch(void* const* d_in, const int* in_sizes, int n_in,
                              void* d_out, int out_size, void* d_ws, size_t ws_size,
                              hipStream_t stream) {
  const float* hs = (const float*)d_in[0];
  const float* Wq = (const float*)d_in[1];
  const float* bq = (const float*)d_in[2];
  const float* Wk = (const float*)d_in[3];
  const float* bk = (const float*)d_in[4];
  const float* Wv = (const float*)d_in[5];
  const float* bv = (const float*)d_in[6];
  const float* Wo = (const float*)d_in[7];
  const float* bo = (const float*)d_in[8];

  char* ws = (char*)d_ws;
  bf16* xb   = (bf16*)(ws + OFF_XB);
  bf16* wqkv = (bf16*)(ws + OFF_WQKV);
  bf16* wob  = (bf16*)(ws + OFF_WO);
  bf16* Qfw  = (bf16*)(ws + OFF_Q);
  bf16* Kfw  = (bf16*)(ws + OFF_K);
  bf16* Vfw  = (bf16*)(ws + OFF_V);
  bf16* ctx  = (bf16*)(ws + OFF_CTX);

  cast_bf16_kernel<<<2048, 256, 0, stream>>>(hs, xb, NTOK * D_ / 4);
  cast4_kernel<<<dim3(256, 4), 256, 0, stream>>>(
      Wq, Wk, Wv, Wo,
      wqkv, wqkv + (size_t)D_ * D_, wqkv + (size_t)2 * D_ * D_, wob,
      D_ * D_ / 4);

  qkv_gemm<<<1560, 256, 0, stream>>>(xb, wqkv, bq, bk, bv, Qfw, Kfw, Vfw);
  attn_kernel<<<BH_, 512, 0, stream>>>(Qfw, Kfw, Vfw, ctx);
  o_gemm<<<1032, 256, 0, stream>>>(ctx, wob, bo, (float*)d_out);
}

// Round 7
// 294.836 us; speedup vs baseline: 1.4305x; 1.4305x over previous
//
#include <hip/hip_runtime.h>

// ChineseCLIP vision attention, MI355X bf16-MFMA pipeline. Round 7:
//  - attn: 512-thread blocks, K+V in 68KB LDS, GROUPED ONLINE SOFTMAX
//    (groups of 4 kt) so the live register set fits ~80 VGPRs ->
//    __launch_bounds__(512) with NO min-waves arg (R6's ",4" capped the
//    unified VGPR+AGPR file at 128 and spilled 550MB to scratch).
//    Target: 2 blocks/CU = 16 waves/CU at minimal 53MB traffic.
//  - qkv: R4 BK=32 m97 K-loop + LDS-transpose epilogue (known 95us).
//  - o_gemm: 64x128 tiles, grid 1032.
// B=32, T=257, D=1024, H=16, HD=64.

#define B_   32
#define T_   257
#define TP   272
#define H_   16
#define HD_  64
#define D_   1024
#define NTOK 8224
#define BH_  512
#define FRAG_PER_BH 17408   // TP*HD elements per (b,h) in frag-major arrays

typedef __bf16 bf16;
typedef __bf16 bf16x4 __attribute__((ext_vector_type(4)));
typedef __bf16 bf16x8 __attribute__((ext_vector_type(8)));
typedef short  s16x4  __attribute__((ext_vector_type(4)));
typedef short  s16x8  __attribute__((ext_vector_type(8)));
typedef float  floatx4 __attribute__((ext_vector_type(4)));

static constexpr size_t SZ_XB   = (size_t)NTOK * D_ * 2;
static constexpr size_t SZ_WQKV = (size_t)3 * D_ * D_ * 2;
static constexpr size_t SZ_W    = (size_t)D_ * D_ * 2;
static constexpr size_t SZ_QK   = (size_t)BH_ * FRAG_PER_BH * 2;

static constexpr size_t OFF_XB   = 0;
static constexpr size_t OFF_WQKV = OFF_XB + SZ_XB;
static constexpr size_t OFF_WO   = OFF_WQKV + SZ_WQKV;
static constexpr size_t OFF_Q    = OFF_WO + SZ_W;
static constexpr size_t OFF_K    = OFF_Q + SZ_QK;
static constexpr size_t OFF_V    = OFF_K + SZ_QK;
static constexpr size_t OFF_CTX  = OFF_V + SZ_QK;

// scale for Q: (1/8) * log2(e) so softmax runs in exp2 domain
#define QSCALE 0.18033688011112042f

#define GLD16(gp, lp)                                                        \
  __builtin_amdgcn_global_load_lds(                                          \
      (const __attribute__((address_space(1))) void*)(gp),                   \
      (__attribute__((address_space(3))) void*)(lp), 16, 0, 0)

// ---------------- fp32 -> bf16 casts ----------------
__global__ void cast_bf16_kernel(const float* __restrict__ src,
                                 bf16* __restrict__ dst, int n4) {
  int i = blockIdx.x * blockDim.x + threadIdx.x;
  int stride = gridDim.x * blockDim.x;
  for (int idx = i; idx < n4; idx += stride) {
    float4 v = reinterpret_cast<const float4*>(src)[idx];
    bf16x4 o;
    o[0] = (bf16)v.x; o[1] = (bf16)v.y; o[2] = (bf16)v.z; o[3] = (bf16)v.w;
    reinterpret_cast<bf16x4*>(dst)[idx] = o;
  }
}

__global__ void cast4_kernel(const float* __restrict__ s0, const float* __restrict__ s1,
                             const float* __restrict__ s2, const float* __restrict__ s3,
                             bf16* __restrict__ d0, bf16* __restrict__ d1,
                             bf16* __restrict__ d2, bf16* __restrict__ d3, int n4) {
  const float* s = (blockIdx.y == 0) ? s0 : (blockIdx.y == 1) ? s1
                   : (blockIdx.y == 2) ? s2 : s3;
  bf16* d = (blockIdx.y == 0) ? d0 : (blockIdx.y == 1) ? d1
            : (blockIdx.y == 2) ? d2 : d3;
  int i = blockIdx.x * blockDim.x + threadIdx.x;
  int stride = gridDim.x * blockDim.x;
  for (int idx = i; idx < n4; idx += stride) {
    float4 v = reinterpret_cast<const float4*>(s)[idx];
    bf16x4 o;
    o[0] = (bf16)v.x; o[1] = (bf16)v.y; o[2] = (bf16)v.z; o[3] = (bf16)v.w;
    reinterpret_cast<bf16x4*>(d)[idx] = o;
  }
}

// Frag-major layouts (element offsets within one bh's 17408 elems):
// Q/K (A/B-op of 16x16x32): [kt(17)][dc(8)][ki(16)][8]  (t=kt*16+ki, d=dc*8+e)
// V   (A-op of 16x16x16, dt-paired): [kt(17)][p(2)][q2(4)][d16(16)][dp(2)][ki(4)]
//     t = kt*16 + q2*4 + ki, d = p*32 + dp*16 + d16.

// ---------------- fused QKV GEMM (R4 BK=32 m97 structure) ----------------
__global__ __launch_bounds__(256) void qkv_gemm(
    const bf16* __restrict__ xb, const bf16* __restrict__ wqkv,
    const float* __restrict__ bq, const float* __restrict__ bk,
    const float* __restrict__ bv,
    bf16* __restrict__ Qf, bf16* __restrict__ Kf, bf16* __restrict__ Vf) {
  __shared__ bf16 smem[9216];          // K-loop: Ash(4096)+Bsh(4096); epi: 128x72
  bf16* Ash = smem;
  bf16* Bsh = smem + 4096;

  const int linear = blockIdx.x;
  const int nbg = ((linear & 7) * 3 + ((linear >> 3) % 3)) * 128;
  const int mbase = (linear / 24) * 128;
  const int tid = threadIdx.x;
  const int lane = tid & 63;
  const int w = tid >> 6;
  const int wr = w >> 1, wc = w & 1;
  const int n15 = lane & 15, quad = lane >> 4;

  const int lrow = lane >> 2;
  const int lseg = (lane & 3) * 8;

  floatx4 acc[4][4] = {};

  for (int k0 = 0; k0 < D_; k0 += 32) {
#pragma unroll
    for (int c = 0; c < 2; c++) {
      int r0 = w * 32 + c * 16;
      int row = r0 + lrow;
      int gm = mbase + row; if (gm > NTOK - 1) gm = NTOK - 1;
      GLD16(xb + (size_t)gm * D_ + k0 + lseg, Ash + r0 * 32);
      GLD16(wqkv + (size_t)(nbg + row) * D_ + k0 + lseg, Bsh + r0 * 32);
    }
    __syncthreads();
    bf16x8 af[4], bfr[4];
#pragma unroll
    for (int i = 0; i < 4; i++) {
      af[i]  = *reinterpret_cast<const bf16x8*>(Ash + (wr * 64 + i * 16 + n15) * 32 + quad * 8);
      bfr[i] = *reinterpret_cast<const bf16x8*>(Bsh + (wc * 64 + i * 16 + n15) * 32 + quad * 8);
    }
#pragma unroll
    for (int i = 0; i < 4; i++)
#pragma unroll
      for (int j = 0; j < 4; j++)
        acc[i][j] = __builtin_amdgcn_mfma_f32_16x16x32_bf16(af[i], bfr[j], acc[i][j], 0, 0, 0);
    __syncthreads();
  }

  // ---- epilogue: LDS transpose + coalesced frag-major stores ----
  const int z = nbg >> 10;
  bf16* zdst = (z == 0) ? Qf : (z == 1) ? Kf : Vf;
  const float scale = (z == 0) ? QSCALE : 1.0f;
  const float* bias = (z == 0) ? bq : (z == 1) ? bk : bv;
  const int zoff = nbg & 1023;

  const int bA = mbase / T_;
  const int tA = mbase - bA * T_;
  const int tEndA = (tA + 128 < T_) ? tA + 128 : T_;
  const int tgA0 = tA >> 4;
  const int nA = ((tEndA - 1) >> 4) - tgA0 + 1;
  int nU = nA, tEndB = 0;
  if (tA + 128 > T_ && bA + 1 < B_) {
    tEndB = tA + 128 - T_;
    nU += ((tEndB - 1) >> 4) + 1;
  }

  for (int half = 0; half < 2; half++) {
    if (wc == half) {
#pragma unroll
      for (int i = 0; i < 4; i++)
#pragma unroll
        for (int j = 0; j < 4; j++) {
          int colL = j * 16 + n15;
          float bval = bias[zoff + half * 64 + colL];
#pragma unroll
          for (int r = 0; r < 4; r++) {
            int rowL = wr * 64 + i * 16 + quad * 4 + r;
            smem[rowL * 72 + colL] = (bf16)((acc[i][j][r] + bval) * scale);
          }
        }
    }
    __syncthreads();
    const int h = (zoff >> 6) + half;
    for (int u = w; u < nU; u += 4) {
      int b, tg, tlo, thi;
      if (u < nA) {
        b = bA; tg = tgA0 + u;
        tlo = (tA > tg * 16) ? tA : tg * 16;
        int te = tg * 16 + 16; thi = (te < tEndA) ? te : tEndA;
      } else {
        b = bA + 1; tg = u - nA;
        tlo = tg * 16;
        int te = tg * 16 + 16; thi = (te < tEndB) ? te : tEndB;
      }
      bf16* gb = zdst + (size_t)(b * H_ + h) * FRAG_PER_BH + tg * 1024;
      if (z != 2) {
        int ki = lane & 15, dc = lane >> 4;
        int t = tg * 16 + ki;
        if (t >= tlo && t < thi) {
          int rowL = b * T_ + t - mbase;
          bf16x8 v0 = *reinterpret_cast<const bf16x8*>(smem + rowL * 72 + dc * 8);
          bf16x8 v1 = *reinterpret_cast<const bf16x8*>(smem + rowL * 72 + 32 + dc * 8);
          *reinterpret_cast<bf16x8*>(gb + dc * 128 + ki * 8) = v0;
          *reinterpret_cast<bf16x8*>(gb + 512 + dc * 128 + ki * 8) = v1;
        }
      } else {
        int q2 = (lane >> 4) & 3, d16 = lane & 15;
        int tb = tg * 16 + q2 * 4;
        bool full = (tb >= tlo) && (tb + 3 < thi);
#pragma unroll
        for (int p = 0; p < 2; p++) {
          bf16x8 vv;
#pragma unroll
          for (int dp = 0; dp < 2; dp++)
#pragma unroll
            for (int ki = 0; ki < 4; ki++) {
              int t = tb + ki;
              int rr = (b * T_ + t - mbase) & 127;   // safe for masked elems
              vv[dp * 4 + ki] = smem[rr * 72 + p * 32 + dp * 16 + d16];
            }
          bf16* cp = gb + (p * 4 + q2) * 128 + d16 * 8;
          if (full) {
            *reinterpret_cast<bf16x8*>(cp) = vv;
          } else {
#pragma unroll
            for (int dp = 0; dp < 2; dp++)
#pragma unroll
              for (int ki = 0; ki < 4; ki++) {
                int t = tb + ki;
                if (t >= tlo && t < thi) cp[dp * 4 + ki] = vv[dp * 4 + ki];
              }
          }
        }
      }
    }
    __syncthreads();
  }
}

// ---------------- fused attention (8 waves/block, K+V LDS, online softmax) --
// grid = 512 (one block per bh), 512 threads; wave w handles qt w, w+8, (16).
// Grouped online softmax (4 kt per group) keeps the live register set ~80
// so the compiler can land <=128 combined VGPR+AGPR -> 2 blocks/CU.
__global__ __launch_bounds__(512) void attn_kernel(
    const bf16* __restrict__ Qf, const bf16* __restrict__ Kf,
    const bf16* __restrict__ Vf, bf16* __restrict__ ctx) {
  __shared__ bf16 smem[34816];   // K (17408) then V (17408) = 68 KB

  const int bh = blockIdx.x;
  const int tid = threadIdx.x;
  const int lane = tid & 63, w = tid >> 6;   // w in 0..7
  const int n15 = lane & 15, quad = lane >> 4;
  const int b = bh >> 4, h = bh & 15;

  const bf16* Qb = Qf + (size_t)bh * FRAG_PER_BH;
  const bf16* Kb = Kf + (size_t)bh * FRAG_PER_BH;
  const bf16* Vb = Vf + (size_t)bh * FRAG_PER_BH;

  // stage K and V: 68 chunks of 1KB over 8 waves
  for (int c = w; c < 68; c += 8) {
    const bf16* src = (c < 34) ? (Kb + c * 512) : (Vb + (c - 34) * 512);
    GLD16(src + lane * 8, smem + c * 512);
  }
  __syncthreads();
  const bf16* Ksh = smem;
  const bf16* Vsh = smem + 17408;

  const int fo = quad * 128 + n15 * 8;

  for (int qt = w; qt < 17; qt += 8) {
    bf16x8 q0 = *reinterpret_cast<const bf16x8*>(Qb + qt * 1024 + fo);
    bf16x8 q1 = *reinterpret_cast<const bf16x8*>(Qb + qt * 1024 + 512 + fo);

    float m = -1e30f, l = 0.f;
    floatx4 o[4] = {};

#pragma unroll
    for (int g = 0; g < 5; g++) {
      const int nk = (g < 4) ? 4 : 1;
      floatx4 s[4];
#pragma unroll
      for (int j = 0; j < nk; j++) {
        const int kt = g * 4 + j;
        bf16x8 ka0 = *reinterpret_cast<const bf16x8*>(Ksh + kt * 1024 + fo);
        bf16x8 ka1 = *reinterpret_cast<const bf16x8*>(Ksh + kt * 1024 + 512 + fo);
        floatx4 c = {};
        c = __builtin_amdgcn_mfma_f32_16x16x32_bf16(ka0, q0, c, 0, 0, 0);
        c = __builtin_amdgcn_mfma_f32_16x16x32_bf16(ka1, q1, c, 0, 0, 0);
        s[j] = c;
      }
      if (g == 4) {
        // keys 257..271 invalid: tile 16 holds keys 256+quad*4+r; only 256 ok
        s[0][1] = -1e30f; s[0][2] = -1e30f; s[0][3] = -1e30f;
        if (quad != 0) s[0][0] = -1e30f;
      }
      float gm = -1e30f;
#pragma unroll
      for (int j = 0; j < nk; j++)
#pragma unroll
        for (int r = 0; r < 4; r++) gm = fmaxf(gm, s[j][r]);
      gm = fmaxf(gm, __shfl_xor(gm, 16));
      gm = fmaxf(gm, __shfl_xor(gm, 32));
      const float mnew = fmaxf(m, gm);
      const float alpha = exp2f(m - mnew);
      m = mnew;
      l *= alpha;
      s16x4 pb[4];
#pragma unroll
      for (int j = 0; j < nk; j++) {
        bf16x4 ph;
#pragma unroll
        for (int r = 0; r < 4; r++) {
          float p = exp2f(s[j][r] - mnew);   // scores pre-scaled by log2e/8
          l += p;
          ph[r] = (bf16)p;
        }
        pb[j] = __builtin_bit_cast(s16x4, ph);
      }
#pragma unroll
      for (int dt = 0; dt < 4; dt++) o[dt] = o[dt] * alpha;
#pragma unroll
      for (int j = 0; j < nk; j++) {
        const int kt = g * 4 + j;
#pragma unroll
        for (int p = 0; p < 2; p++) {
          bf16x8 vv = *reinterpret_cast<const bf16x8*>(
              Vsh + ((kt * 2 + p) * 4 + quad) * 128 + n15 * 8);
          s16x8 v16 = __builtin_bit_cast(s16x8, vv);
          s16x4 vlo = __builtin_shufflevector(v16, v16, 0, 1, 2, 3);
          s16x4 vhi = __builtin_shufflevector(v16, v16, 4, 5, 6, 7);
          o[p * 2]     = __builtin_amdgcn_mfma_f32_16x16x16bf16_1k(vlo, pb[j], o[p * 2], 0, 0, 0);
          o[p * 2 + 1] = __builtin_amdgcn_mfma_f32_16x16x16bf16_1k(vhi, pb[j], o[p * 2 + 1], 0, 0, 0);
        }
      }
    }

    l += __shfl_xor(l, 16);
    l += __shfl_xor(l, 32);

    int q = qt * 16 + n15;
    if (q < T_) {
      float inv = 1.0f / l;
      size_t ob = ((size_t)(b * T_ + q)) * D_ + h * 64 + quad * 4;
#pragma unroll
      for (int dt = 0; dt < 4; dt++) {
        bf16x4 ov;
#pragma unroll
        for (int r = 0; r < 4; r++) ov[r] = (bf16)(o[dt][r] * inv);
        *reinterpret_cast<bf16x4*>(ctx + ob + dt * 16) = ov;
      }
    }
  }
}

// ---------------- output projection GEMM (64x128 tile, fp32 out) ----------------
// grid = 1032 = 129 m-tiles x 8 n-tiles (n fastest for ctx A-tile reuse).
__global__ __launch_bounds__(256) void o_gemm(
    const bf16* __restrict__ ctx, const bf16* __restrict__ wo,
    const float* __restrict__ bo, float* __restrict__ out) {
  __shared__ bf16 Ash[64 * 32];
  __shared__ bf16 Bsh[128 * 32];

  const int linear = blockIdx.x;
  const int nbase = (linear & 7) * 128;
  const int mbase = (linear >> 3) * 64;
  const int tid = threadIdx.x;
  const int lane = tid & 63;
  const int w = tid >> 6;
  const int wr = w >> 1, wc = w & 1;   // wave tile: 32(m) x 64(n)
  const int n15 = lane & 15, quad = lane >> 4;

  const int lrow = lane >> 2;
  const int lseg = (lane & 3) * 8;

  floatx4 acc[2][4] = {};

  for (int k0 = 0; k0 < D_; k0 += 32) {
    {
      int r0 = w * 16;
      int gm = mbase + r0 + lrow; if (gm > NTOK - 1) gm = NTOK - 1;
      GLD16(ctx + (size_t)gm * D_ + k0 + lseg, Ash + r0 * 32);
    }
#pragma unroll
    for (int c = 0; c < 2; c++) {
      int r0 = w * 32 + c * 16;
      GLD16(wo + (size_t)(nbase + r0 + lrow) * D_ + k0 + lseg, Bsh + r0 * 32);
    }
    __syncthreads();
    bf16x8 af[2], bfr[4];
#pragma unroll
    for (int i = 0; i < 2; i++)
      af[i] = *reinterpret_cast<const bf16x8*>(Ash + (wr * 32 + i * 16 + n15) * 32 + quad * 8);
#pragma unroll
    for (int j = 0; j < 4; j++)
      bfr[j] = *reinterpret_cast<const bf16x8*>(Bsh + (wc * 64 + j * 16 + n15) * 32 + quad * 8);
#pragma unroll
    for (int i = 0; i < 2; i++)
#pragma unroll
      for (int j = 0; j < 4; j++)
        acc[i][j] = __builtin_amdgcn_mfma_f32_16x16x32_bf16(af[i], bfr[j], acc[i][j], 0, 0, 0);
    __syncthreads();
  }

#pragma unroll
  for (int i = 0; i < 2; i++) {
    int rowb = mbase + wr * 32 + i * 16 + quad * 4;
#pragma unroll
    for (int j = 0; j < 4; j++) {
      int col = nbase + wc * 64 + j * 16 + n15;
      float bval = bo[col];
#pragma unroll
      for (int r = 0; r < 4; r++) {
        int m = rowb + r;
        if (m < NTOK) out[(size_t)m * D_ + col] = acc[i][j][r] + bval;
      }
    }
  }
}

extern "C" void kernel_launch(void* const* d_in, const int* in_sizes, int n_in,
                              void* d_out, int out_size, void* d_ws, size_t ws_size,
                              hipStream_t stream) {
  const float* hs = (const float*)d_in[0];
  const float* Wq = (const float*)d_in[1];
  const float* bq = (const float*)d_in[2];
  const float* Wk = (const float*)d_in[3];
  const float* bk = (const float*)d_in[4];
  const float* Wv = (const float*)d_in[5];
  const float* bv = (const float*)d_in[6];
  const float* Wo = (const float*)d_in[7];
  const float* bo = (const float*)d_in[8];

  char* ws = (char*)d_ws;
  bf16* xb   = (bf16*)(ws + OFF_XB);
  bf16* wqkv = (bf16*)(ws + OFF_WQKV);
  bf16* wob  = (bf16*)(ws + OFF_WO);
  bf16* Qfw  = (bf16*)(ws + OFF_Q);
  bf16* Kfw  = (bf16*)(ws + OFF_K);
  bf16* Vfw  = (bf16*)(ws + OFF_V);
  bf16* ctx  = (bf16*)(ws + OFF_CTX);

  cast_bf16_kernel<<<2048, 256, 0, stream>>>(hs, xb, NTOK * D_ / 4);
  cast4_kernel<<<dim3(256, 4), 256, 0, stream>>>(
      Wq, Wk, Wv, Wo,
      wqkv, wqkv + (size_t)D_ * D_, wqkv + (size_t)2 * D_ * D_, wob,
      D_ * D_ / 4);

  qkv_gemm<<<1560, 256, 0, stream>>>(xb, wqkv, bq, bk, bv, Qfw, Kfw, Vfw);
  attn_kernel<<<BH_, 512, 0, stream>>>(Qfw, Kfw, Vfw, ctx);
  o_gemm<<<1032, 256, 0, stream>>>(ctx, wob, bo, (float*)d_out);
}

// Round 8
// 255.947 us; speedup vs baseline: 1.6479x; 1.1519x over previous
//
#include <hip/hip_runtime.h>

// ChineseCLIP vision attention, MI355X bf16-MFMA pipeline. Round 8:
//  - attn: 512-thread blocks, K+V in 68KB LDS, online softmax in groups of
//    4 kt with "#pragma unroll 1" (R7's full unroll let the scheduler hoist
//    all 17 kt -> live range > the 128-VGPR cap LLVM derives from
//    2-blocks/CU LDS occupancy -> 160MB scratch spill). kt=16 is a separate
//    masked tail. Target: VGPR<=128, no spill, 16 waves/CU.
//  - qkv: R4 BK=32 m97 K-loop + LDS-transpose epilogue (stable ~93us).
//  - o_gemm: 64x128 tiles, grid 1032.
// B=32, T=257, D=1024, H=16, HD=64.

#define B_   32
#define T_   257
#define TP   272
#define H_   16
#define HD_  64
#define D_   1024
#define NTOK 8224
#define BH_  512
#define FRAG_PER_BH 17408   // TP*HD elements per (b,h) in frag-major arrays

typedef __bf16 bf16;
typedef __bf16 bf16x4 __attribute__((ext_vector_type(4)));
typedef __bf16 bf16x8 __attribute__((ext_vector_type(8)));
typedef short  s16x4  __attribute__((ext_vector_type(4)));
typedef short  s16x8  __attribute__((ext_vector_type(8)));
typedef float  floatx4 __attribute__((ext_vector_type(4)));

static constexpr size_t SZ_XB   = (size_t)NTOK * D_ * 2;
static constexpr size_t SZ_WQKV = (size_t)3 * D_ * D_ * 2;
static constexpr size_t SZ_W    = (size_t)D_ * D_ * 2;
static constexpr size_t SZ_QK   = (size_t)BH_ * FRAG_PER_BH * 2;

static constexpr size_t OFF_XB   = 0;
static constexpr size_t OFF_WQKV = OFF_XB + SZ_XB;
static constexpr size_t OFF_WO   = OFF_WQKV + SZ_WQKV;
static constexpr size_t OFF_Q    = OFF_WO + SZ_W;
static constexpr size_t OFF_K    = OFF_Q + SZ_QK;
static constexpr size_t OFF_V    = OFF_K + SZ_QK;
static constexpr size_t OFF_CTX  = OFF_V + SZ_QK;

// scale for Q: (1/8) * log2(e) so softmax runs in exp2 domain
#define QSCALE 0.18033688011112042f

#define GLD16(gp, lp)                                                        \
  __builtin_amdgcn_global_load_lds(                                          \
      (const __attribute__((address_space(1))) void*)(gp),                   \
      (__attribute__((address_space(3))) void*)(lp), 16, 0, 0)

// ---------------- fp32 -> bf16 casts ----------------
__global__ void cast_bf16_kernel(const float* __restrict__ src,
                                 bf16* __restrict__ dst, int n4) {
  int i = blockIdx.x * blockDim.x + threadIdx.x;
  int stride = gridDim.x * blockDim.x;
  for (int idx = i; idx < n4; idx += stride) {
    float4 v = reinterpret_cast<const float4*>(src)[idx];
    bf16x4 o;
    o[0] = (bf16)v.x; o[1] = (bf16)v.y; o[2] = (bf16)v.z; o[3] = (bf16)v.w;
    reinterpret_cast<bf16x4*>(dst)[idx] = o;
  }
}

__global__ void cast4_kernel(const float* __restrict__ s0, const float* __restrict__ s1,
                             const float* __restrict__ s2, const float* __restrict__ s3,
                             bf16* __restrict__ d0, bf16* __restrict__ d1,
                             bf16* __restrict__ d2, bf16* __restrict__ d3, int n4) {
  const float* s = (blockIdx.y == 0) ? s0 : (blockIdx.y == 1) ? s1
                   : (blockIdx.y == 2) ? s2 : s3;
  bf16* d = (blockIdx.y == 0) ? d0 : (blockIdx.y == 1) ? d1
            : (blockIdx.y == 2) ? d2 : d3;
  int i = blockIdx.x * blockDim.x + threadIdx.x;
  int stride = gridDim.x * blockDim.x;
  for (int idx = i; idx < n4; idx += stride) {
    float4 v = reinterpret_cast<const float4*>(s)[idx];
    bf16x4 o;
    o[0] = (bf16)v.x; o[1] = (bf16)v.y; o[2] = (bf16)v.z; o[3] = (bf16)v.w;
    reinterpret_cast<bf16x4*>(d)[idx] = o;
  }
}

// Frag-major layouts (element offsets within one bh's 17408 elems):
// Q/K (A/B-op of 16x16x32): [kt(17)][dc(8)][ki(16)][8]  (t=kt*16+ki, d=dc*8+e)
// V   (A-op of 16x16x16, dt-paired): [kt(17)][p(2)][q2(4)][d16(16)][dp(2)][ki(4)]
//     t = kt*16 + q2*4 + ki, d = p*32 + dp*16 + d16.

// ---------------- fused QKV GEMM (R4 BK=32 m97 structure) ----------------
__global__ __launch_bounds__(256) void qkv_gemm(
    const bf16* __restrict__ xb, const bf16* __restrict__ wqkv,
    const float* __restrict__ bq, const float* __restrict__ bk,
    const float* __restrict__ bv,
    bf16* __restrict__ Qf, bf16* __restrict__ Kf, bf16* __restrict__ Vf) {
  __shared__ bf16 smem[9216];          // K-loop: Ash(4096)+Bsh(4096); epi: 128x72
  bf16* Ash = smem;
  bf16* Bsh = smem + 4096;

  const int linear = blockIdx.x;
  const int nbg = ((linear & 7) * 3 + ((linear >> 3) % 3)) * 128;
  const int mbase = (linear / 24) * 128;
  const int tid = threadIdx.x;
  const int lane = tid & 63;
  const int w = tid >> 6;
  const int wr = w >> 1, wc = w & 1;
  const int n15 = lane & 15, quad = lane >> 4;

  const int lrow = lane >> 2;
  const int lseg = (lane & 3) * 8;

  floatx4 acc[4][4] = {};

  for (int k0 = 0; k0 < D_; k0 += 32) {
#pragma unroll
    for (int c = 0; c < 2; c++) {
      int r0 = w * 32 + c * 16;
      int row = r0 + lrow;
      int gm = mbase + row; if (gm > NTOK - 1) gm = NTOK - 1;
      GLD16(xb + (size_t)gm * D_ + k0 + lseg, Ash + r0 * 32);
      GLD16(wqkv + (size_t)(nbg + row) * D_ + k0 + lseg, Bsh + r0 * 32);
    }
    __syncthreads();
    bf16x8 af[4], bfr[4];
#pragma unroll
    for (int i = 0; i < 4; i++) {
      af[i]  = *reinterpret_cast<const bf16x8*>(Ash + (wr * 64 + i * 16 + n15) * 32 + quad * 8);
      bfr[i] = *reinterpret_cast<const bf16x8*>(Bsh + (wc * 64 + i * 16 + n15) * 32 + quad * 8);
    }
#pragma unroll
    for (int i = 0; i < 4; i++)
#pragma unroll
      for (int j = 0; j < 4; j++)
        acc[i][j] = __builtin_amdgcn_mfma_f32_16x16x32_bf16(af[i], bfr[j], acc[i][j], 0, 0, 0);
    __syncthreads();
  }

  // ---- epilogue: LDS transpose + coalesced frag-major stores ----
  const int z = nbg >> 10;
  bf16* zdst = (z == 0) ? Qf : (z == 1) ? Kf : Vf;
  const float scale = (z == 0) ? QSCALE : 1.0f;
  const float* bias = (z == 0) ? bq : (z == 1) ? bk : bv;
  const int zoff = nbg & 1023;

  const int bA = mbase / T_;
  const int tA = mbase - bA * T_;
  const int tEndA = (tA + 128 < T_) ? tA + 128 : T_;
  const int tgA0 = tA >> 4;
  const int nA = ((tEndA - 1) >> 4) - tgA0 + 1;
  int nU = nA, tEndB = 0;
  if (tA + 128 > T_ && bA + 1 < B_) {
    tEndB = tA + 128 - T_;
    nU += ((tEndB - 1) >> 4) + 1;
  }

  for (int half = 0; half < 2; half++) {
    if (wc == half) {
#pragma unroll
      for (int i = 0; i < 4; i++)
#pragma unroll
        for (int j = 0; j < 4; j++) {
          int colL = j * 16 + n15;
          float bval = bias[zoff + half * 64 + colL];
#pragma unroll
          for (int r = 0; r < 4; r++) {
            int rowL = wr * 64 + i * 16 + quad * 4 + r;
            smem[rowL * 72 + colL] = (bf16)((acc[i][j][r] + bval) * scale);
          }
        }
    }
    __syncthreads();
    const int h = (zoff >> 6) + half;
    for (int u = w; u < nU; u += 4) {
      int b, tg, tlo, thi;
      if (u < nA) {
        b = bA; tg = tgA0 + u;
        tlo = (tA > tg * 16) ? tA : tg * 16;
        int te = tg * 16 + 16; thi = (te < tEndA) ? te : tEndA;
      } else {
        b = bA + 1; tg = u - nA;
        tlo = tg * 16;
        int te = tg * 16 + 16; thi = (te < tEndB) ? te : tEndB;
      }
      bf16* gb = zdst + (size_t)(b * H_ + h) * FRAG_PER_BH + tg * 1024;
      if (z != 2) {
        int ki = lane & 15, dc = lane >> 4;
        int t = tg * 16 + ki;
        if (t >= tlo && t < thi) {
          int rowL = b * T_ + t - mbase;
          bf16x8 v0 = *reinterpret_cast<const bf16x8*>(smem + rowL * 72 + dc * 8);
          bf16x8 v1 = *reinterpret_cast<const bf16x8*>(smem + rowL * 72 + 32 + dc * 8);
          *reinterpret_cast<bf16x8*>(gb + dc * 128 + ki * 8) = v0;
          *reinterpret_cast<bf16x8*>(gb + 512 + dc * 128 + ki * 8) = v1;
        }
      } else {
        int q2 = (lane >> 4) & 3, d16 = lane & 15;
        int tb = tg * 16 + q2 * 4;
        bool full = (tb >= tlo) && (tb + 3 < thi);
#pragma unroll
        for (int p = 0; p < 2; p++) {
          bf16x8 vv;
#pragma unroll
          for (int dp = 0; dp < 2; dp++)
#pragma unroll
            for (int ki = 0; ki < 4; ki++) {
              int t = tb + ki;
              int rr = (b * T_ + t - mbase) & 127;   // safe for masked elems
              vv[dp * 4 + ki] = smem[rr * 72 + p * 32 + dp * 16 + d16];
            }
          bf16* cp = gb + (p * 4 + q2) * 128 + d16 * 8;
          if (full) {
            *reinterpret_cast<bf16x8*>(cp) = vv;
          } else {
#pragma unroll
            for (int dp = 0; dp < 2; dp++)
#pragma unroll
              for (int ki = 0; ki < 4; ki++) {
                int t = tb + ki;
                if (t >= tlo && t < thi) cp[dp * 4 + ki] = vv[dp * 4 + ki];
              }
          }
        }
      }
    }
    __syncthreads();
  }
}

// ---------------- fused attention (8 waves/block, K+V LDS, online softmax) --
// grid = 512 (one block per bh), 512 threads; wave w handles qt w, w+8, (16).
// Groups of 4 kt, "#pragma unroll 1" so the live set stays < the 128-VGPR
// cap LLVM derives from 2-blocks/CU LDS occupancy. kt=16 is a masked tail.
__global__ __launch_bounds__(512) void attn_kernel(
    const bf16* __restrict__ Qf, const bf16* __restrict__ Kf,
    const bf16* __restrict__ Vf, bf16* __restrict__ ctx) {
  __shared__ bf16 smem[34816];   // K (17408) then V (17408) = 68 KB

  const int bh = blockIdx.x;
  const int tid = threadIdx.x;
  const int lane = tid & 63, w = tid >> 6;   // w in 0..7
  const int n15 = lane & 15, quad = lane >> 4;
  const int b = bh >> 4, h = bh & 15;

  const bf16* Qb = Qf + (size_t)bh * FRAG_PER_BH;
  const bf16* Kb = Kf + (size_t)bh * FRAG_PER_BH;
  const bf16* Vb = Vf + (size_t)bh * FRAG_PER_BH;

  // stage K and V: 68 chunks of 1KB over 8 waves
  for (int c = w; c < 68; c += 8) {
    const bf16* src = (c < 34) ? (Kb + c * 512) : (Vb + (c - 34) * 512);
    GLD16(src + lane * 8, smem + c * 512);
  }
  __syncthreads();
  const bf16* Ksh = smem;
  const bf16* Vsh = smem + 17408;

  const int fo = quad * 128 + n15 * 8;

#pragma unroll 1
  for (int qt = w; qt < 17; qt += 8) {
    bf16x8 q0 = *reinterpret_cast<const bf16x8*>(Qb + qt * 1024 + fo);
    bf16x8 q1 = *reinterpret_cast<const bf16x8*>(Qb + qt * 1024 + 512 + fo);

    float m = -1e30f, l = 0.f;
    floatx4 o[4] = {};

#pragma unroll 1
    for (int g = 0; g < 4; g++) {
      floatx4 s[4];
#pragma unroll
      for (int j = 0; j < 4; j++) {
        const int kt = g * 4 + j;
        bf16x8 ka0 = *reinterpret_cast<const bf16x8*>(Ksh + kt * 1024 + fo);
        bf16x8 ka1 = *reinterpret_cast<const bf16x8*>(Ksh + kt * 1024 + 512 + fo);
        floatx4 c = {};
        c = __builtin_amdgcn_mfma_f32_16x16x32_bf16(ka0, q0, c, 0, 0, 0);
        c = __builtin_amdgcn_mfma_f32_16x16x32_bf16(ka1, q1, c, 0, 0, 0);
        s[j] = c;
      }
      float gm = -1e30f;
#pragma unroll
      for (int j = 0; j < 4; j++)
#pragma unroll
        for (int r = 0; r < 4; r++) gm = fmaxf(gm, s[j][r]);
      gm = fmaxf(gm, __shfl_xor(gm, 16));
      gm = fmaxf(gm, __shfl_xor(gm, 32));
      const float mnew = fmaxf(m, gm);
      const float alpha = exp2f(m - mnew);
      m = mnew;
      l *= alpha;
      s16x4 pb[4];
#pragma unroll
      for (int j = 0; j < 4; j++) {
        bf16x4 ph;
#pragma unroll
        for (int r = 0; r < 4; r++) {
          float p = exp2f(s[j][r] - mnew);   // scores pre-scaled by log2e/8
          l += p;
          ph[r] = (bf16)p;
        }
        pb[j] = __builtin_bit_cast(s16x4, ph);
      }
#pragma unroll
      for (int dt = 0; dt < 4; dt++) o[dt] = o[dt] * alpha;
#pragma unroll
      for (int j = 0; j < 4; j++) {
        const int kt = g * 4 + j;
#pragma unroll
        for (int p = 0; p < 2; p++) {
          bf16x8 vv = *reinterpret_cast<const bf16x8*>(
              Vsh + ((kt * 2 + p) * 4 + quad) * 128 + n15 * 8);
          s16x8 v16 = __builtin_bit_cast(s16x8, vv);
          s16x4 vlo = __builtin_shufflevector(v16, v16, 0, 1, 2, 3);
          s16x4 vhi = __builtin_shufflevector(v16, v16, 4, 5, 6, 7);
          o[p * 2]     = __builtin_amdgcn_mfma_f32_16x16x16bf16_1k(vlo, pb[j], o[p * 2], 0, 0, 0);
          o[p * 2 + 1] = __builtin_amdgcn_mfma_f32_16x16x16bf16_1k(vhi, pb[j], o[p * 2 + 1], 0, 0, 0);
        }
      }
    }

    // ---- tail: kt = 16 (only key 256 valid: quad 0, r 0) ----
    {
      bf16x8 ka0 = *reinterpret_cast<const bf16x8*>(Ksh + 16 * 1024 + fo);
      bf16x8 ka1 = *reinterpret_cast<const bf16x8*>(Ksh + 16 * 1024 + 512 + fo);
      floatx4 c = {};
      c = __builtin_amdgcn_mfma_f32_16x16x32_bf16(ka0, q0, c, 0, 0, 0);
      c = __builtin_amdgcn_mfma_f32_16x16x32_bf16(ka1, q1, c, 0, 0, 0);
      c[1] = -1e30f; c[2] = -1e30f; c[3] = -1e30f;
      if (quad != 0) c[0] = -1e30f;
      float gm = fmaxf(fmaxf(c[0], c[1]), fmaxf(c[2], c[3]));
      gm = fmaxf(gm, __shfl_xor(gm, 16));
      gm = fmaxf(gm, __shfl_xor(gm, 32));
      const float mnew = fmaxf(m, gm);
      const float alpha = exp2f(m - mnew);
      l *= alpha;
      bf16x4 ph;
#pragma unroll
      for (int r = 0; r < 4; r++) {
        float p = exp2f(c[r] - mnew);
        l += p;
        ph[r] = (bf16)p;
      }
      s16x4 pbt = __builtin_bit_cast(s16x4, ph);
#pragma unroll
      for (int dt = 0; dt < 4; dt++) o[dt] = o[dt] * alpha;
#pragma unroll
      for (int p = 0; p < 2; p++) {
        bf16x8 vv = *reinterpret_cast<const bf16x8*>(
            Vsh + ((16 * 2 + p) * 4 + quad) * 128 + n15 * 8);
        s16x8 v16 = __builtin_bit_cast(s16x8, vv);
        s16x4 vlo = __builtin_shufflevector(v16, v16, 0, 1, 2, 3);
        s16x4 vhi = __builtin_shufflevector(v16, v16, 4, 5, 6, 7);
        o[p * 2]     = __builtin_amdgcn_mfma_f32_16x16x16bf16_1k(vlo, pbt, o[p * 2], 0, 0, 0);
        o[p * 2 + 1] = __builtin_amdgcn_mfma_f32_16x16x16bf16_1k(vhi, pbt, o[p * 2 + 1], 0, 0, 0);
      }
    }

    l += __shfl_xor(l, 16);
    l += __shfl_xor(l, 32);

    int q = qt * 16 + n15;
    if (q < T_) {
      float inv = 1.0f / l;
      size_t ob = ((size_t)(b * T_ + q)) * D_ + h * 64 + quad * 4;
#pragma unroll
      for (int dt = 0; dt < 4; dt++) {
        bf16x4 ov;
#pragma unroll
        for (int r = 0; r < 4; r++) ov[r] = (bf16)(o[dt][r] * inv);
        *reinterpret_cast<bf16x4*>(ctx + ob + dt * 16) = ov;
      }
    }
  }
}

// ---------------- output projection GEMM (64x128 tile, fp32 out) ----------------
// grid = 1032 = 129 m-tiles x 8 n-tiles (n fastest for ctx A-tile reuse).
__global__ __launch_bounds__(256) void o_gemm(
    const bf16* __restrict__ ctx, const bf16* __restrict__ wo,
    const float* __restrict__ bo, float* __restrict__ out) {
  __shared__ bf16 Ash[64 * 32];
  __shared__ bf16 Bsh[128 * 32];

  const int linear = blockIdx.x;
  const int nbase = (linear & 7) * 128;
  const int mbase = (linear >> 3) * 64;
  const int tid = threadIdx.x;
  const int lane = tid & 63;
  const int w = tid >> 6;
  const int wr = w >> 1, wc = w & 1;   // wave tile: 32(m) x 64(n)
  const int n15 = lane & 15, quad = lane >> 4;

  const int lrow = lane >> 2;
  const int lseg = (lane & 3) * 8;

  floatx4 acc[2][4] = {};

  for (int k0 = 0; k0 < D_; k0 += 32) {
    {
      int r0 = w * 16;
      int gm = mbase + r0 + lrow; if (gm > NTOK - 1) gm = NTOK - 1;
      GLD16(ctx + (size_t)gm * D_ + k0 + lseg, Ash + r0 * 32);
    }
#pragma unroll
    for (int c = 0; c < 2; c++) {
      int r0 = w * 32 + c * 16;
      GLD16(wo + (size_t)(nbase + r0 + lrow) * D_ + k0 + lseg, Bsh + r0 * 32);
    }
    __syncthreads();
    bf16x8 af[2], bfr[4];
#pragma unroll
    for (int i = 0; i < 2; i++)
      af[i] = *reinterpret_cast<const bf16x8*>(Ash + (wr * 32 + i * 16 + n15) * 32 + quad * 8);
#pragma unroll
    for (int j = 0; j < 4; j++)
      bfr[j] = *reinterpret_cast<const bf16x8*>(Bsh + (wc * 64 + j * 16 + n15) * 32 + quad * 8);
#pragma unroll
    for (int i = 0; i < 2; i++)
#pragma unroll
      for (int j = 0; j < 4; j++)
        acc[i][j] = __builtin_amdgcn_mfma_f32_16x16x32_bf16(af[i], bfr[j], acc[i][j], 0, 0, 0);
    __syncthreads();
  }

#pragma unroll
  for (int i = 0; i < 2; i++) {
    int rowb = mbase + wr * 32 + i * 16 + quad * 4;
#pragma unroll
    for (int j = 0; j < 4; j++) {
      int col = nbase + wc * 64 + j * 16 + n15;
      float bval = bo[col];
#pragma unroll
      for (int r = 0; r < 4; r++) {
        int m = rowb + r;
        if (m < NTOK) out[(size_t)m * D_ + col] = acc[i][j][r] + bval;
      }
    }
  }
}

extern "C" void kernel_launch(void* const* d_in, const int* in_sizes, int n_in,
                              void* d_out, int out_size, void* d_ws, size_t ws_size,
                              hipStream_t stream) {
  const float* hs = (const float*)d_in[0];
  const float* Wq = (const float*)d_in[1];
  const float* bq = (const float*)d_in[2];
  const float* Wk = (const float*)d_in[3];
  const float* bk = (const float*)d_in[4];
  const float* Wv = (const float*)d_in[5];
  const float* bv = (const float*)d_in[6];
  const float* Wo = (const float*)d_in[7];
  const float* bo = (const float*)d_in[8];

  char* ws = (char*)d_ws;
  bf16* xb   = (bf16*)(ws + OFF_XB);
  bf16* wqkv = (bf16*)(ws + OFF_WQKV);
  bf16* wob  = (bf16*)(ws + OFF_WO);
  bf16* Qfw  = (bf16*)(ws + OFF_Q);
  bf16* Kfw  = (bf16*)(ws + OFF_K);
  bf16* Vfw  = (bf16*)(ws + OFF_V);
  bf16* ctx  = (bf16*)(ws + OFF_CTX);

  cast_bf16_kernel<<<2048, 256, 0, stream>>>(hs, xb, NTOK * D_ / 4);
  cast4_kernel<<<dim3(256, 4), 256, 0, stream>>>(
      Wq, Wk, Wv, Wo,
      wqkv, wqkv + (size_t)D_ * D_, wqkv + (size_t)2 * D_ * D_, wob,
      D_ * D_ / 4);

  qkv_gemm<<<1560, 256, 0, stream>>>(xb, wqkv, bq, bk, bv, Qfw, Kfw, Vfw);
  attn_kernel<<<BH_, 512, 0, stream>>>(Qfw, Kfw, Vfw, ctx);
  o_gemm<<<1032, 256, 0, stream>>>(ctx, wob, bo, (float*)d_out);
}

// Round 9
// 254.000 us; speedup vs baseline: 1.6605x; 1.0077x over previous
//
#include <hip/hip_runtime.h>

// ChineseCLIP vision attention, MI355X bf16-MFMA pipeline. Round 9:
//  - attn: streamed online softmax in GROUPS OF 2 kt (live set ~70 VGPR,
//    provably under the 128-VGPR cap from 2-blocks/CU LDS occupancy; R8's
//    groups-of-4 sat at the edge and still spilled). Otherwise identical.
//  - o_gemm: reverted to the known-good R4 128x128 body (same K-loop as
//    qkv), grid 520 -- removes the unverified 64x128 variant.
//  - qkv: unchanged (stable ~95us).
// B=32, T=257, D=1024, H=16, HD=64.

#define B_   32
#define T_   257
#define TP   272
#define H_   16
#define HD_  64
#define D_   1024
#define NTOK 8224
#define BH_  512
#define FRAG_PER_BH 17408   // TP*HD elements per (b,h) in frag-major arrays

typedef __bf16 bf16;
typedef __bf16 bf16x4 __attribute__((ext_vector_type(4)));
typedef __bf16 bf16x8 __attribute__((ext_vector_type(8)));
typedef short  s16x4  __attribute__((ext_vector_type(4)));
typedef short  s16x8  __attribute__((ext_vector_type(8)));
typedef float  floatx4 __attribute__((ext_vector_type(4)));

static constexpr size_t SZ_XB   = (size_t)NTOK * D_ * 2;
static constexpr size_t SZ_WQKV = (size_t)3 * D_ * D_ * 2;
static constexpr size_t SZ_W    = (size_t)D_ * D_ * 2;
static constexpr size_t SZ_QK   = (size_t)BH_ * FRAG_PER_BH * 2;

static constexpr size_t OFF_XB   = 0;
static constexpr size_t OFF_WQKV = OFF_XB + SZ_XB;
static constexpr size_t OFF_WO   = OFF_WQKV + SZ_WQKV;
static constexpr size_t OFF_Q    = OFF_WO + SZ_W;
static constexpr size_t OFF_K    = OFF_Q + SZ_QK;
static constexpr size_t OFF_V    = OFF_K + SZ_QK;
static constexpr size_t OFF_CTX  = OFF_V + SZ_QK;

// scale for Q: (1/8) * log2(e) so softmax runs in exp2 domain
#define QSCALE 0.18033688011112042f

#define GLD16(gp, lp)                                                        \
  __builtin_amdgcn_global_load_lds(                                          \
      (const __attribute__((address_space(1))) void*)(gp),                   \
      (__attribute__((address_space(3))) void*)(lp), 16, 0, 0)

// ---------------- fp32 -> bf16 casts ----------------
__global__ void cast_bf16_kernel(const float* __restrict__ src,
                                 bf16* __restrict__ dst, int n4) {
  int i = blockIdx.x * blockDim.x + threadIdx.x;
  int stride = gridDim.x * blockDim.x;
  for (int idx = i; idx < n4; idx += stride) {
    float4 v = reinterpret_cast<const float4*>(src)[idx];
    bf16x4 o;
    o[0] = (bf16)v.x; o[1] = (bf16)v.y; o[2] = (bf16)v.z; o[3] = (bf16)v.w;
    reinterpret_cast<bf16x4*>(dst)[idx] = o;
  }
}

__global__ void cast4_kernel(const float* __restrict__ s0, const float* __restrict__ s1,
                             const float* __restrict__ s2, const float* __restrict__ s3,
                             bf16* __restrict__ d0, bf16* __restrict__ d1,
                             bf16* __restrict__ d2, bf16* __restrict__ d3, int n4) {
  const float* s = (blockIdx.y == 0) ? s0 : (blockIdx.y == 1) ? s1
                   : (blockIdx.y == 2) ? s2 : s3;
  bf16* d = (blockIdx.y == 0) ? d0 : (blockIdx.y == 1) ? d1
            : (blockIdx.y == 2) ? d2 : d3;
  int i = blockIdx.x * blockDim.x + threadIdx.x;
  int stride = gridDim.x * blockDim.x;
  for (int idx = i; idx < n4; idx += stride) {
    float4 v = reinterpret_cast<const float4*>(s)[idx];
    bf16x4 o;
    o[0] = (bf16)v.x; o[1] = (bf16)v.y; o[2] = (bf16)v.z; o[3] = (bf16)v.w;
    reinterpret_cast<bf16x4*>(d)[idx] = o;
  }
}

// Frag-major layouts (element offsets within one bh's 17408 elems):
// Q/K (A/B-op of 16x16x32): [kt(17)][dc(8)][ki(16)][8]  (t=kt*16+ki, d=dc*8+e)
// V   (A-op of 16x16x16, dt-paired): [kt(17)][p(2)][q2(4)][d16(16)][dp(2)][ki(4)]
//     t = kt*16 + q2*4 + ki, d = p*32 + dp*16 + d16.

// ---------------- fused QKV GEMM (R4 BK=32 m97 structure) ----------------
__global__ __launch_bounds__(256) void qkv_gemm(
    const bf16* __restrict__ xb, const bf16* __restrict__ wqkv,
    const float* __restrict__ bq, const float* __restrict__ bk,
    const float* __restrict__ bv,
    bf16* __restrict__ Qf, bf16* __restrict__ Kf, bf16* __restrict__ Vf) {
  __shared__ bf16 smem[9216];          // K-loop: Ash(4096)+Bsh(4096); epi: 128x72
  bf16* Ash = smem;
  bf16* Bsh = smem + 4096;

  const int linear = blockIdx.x;
  const int nbg = ((linear & 7) * 3 + ((linear >> 3) % 3)) * 128;
  const int mbase = (linear / 24) * 128;
  const int tid = threadIdx.x;
  const int lane = tid & 63;
  const int w = tid >> 6;
  const int wr = w >> 1, wc = w & 1;
  const int n15 = lane & 15, quad = lane >> 4;

  const int lrow = lane >> 2;
  const int lseg = (lane & 3) * 8;

  floatx4 acc[4][4] = {};

  for (int k0 = 0; k0 < D_; k0 += 32) {
#pragma unroll
    for (int c = 0; c < 2; c++) {
      int r0 = w * 32 + c * 16;
      int row = r0 + lrow;
      int gm = mbase + row; if (gm > NTOK - 1) gm = NTOK - 1;
      GLD16(xb + (size_t)gm * D_ + k0 + lseg, Ash + r0 * 32);
      GLD16(wqkv + (size_t)(nbg + row) * D_ + k0 + lseg, Bsh + r0 * 32);
    }
    __syncthreads();
    bf16x8 af[4], bfr[4];
#pragma unroll
    for (int i = 0; i < 4; i++) {
      af[i]  = *reinterpret_cast<const bf16x8*>(Ash + (wr * 64 + i * 16 + n15) * 32 + quad * 8);
      bfr[i] = *reinterpret_cast<const bf16x8*>(Bsh + (wc * 64 + i * 16 + n15) * 32 + quad * 8);
    }
#pragma unroll
    for (int i = 0; i < 4; i++)
#pragma unroll
      for (int j = 0; j < 4; j++)
        acc[i][j] = __builtin_amdgcn_mfma_f32_16x16x32_bf16(af[i], bfr[j], acc[i][j], 0, 0, 0);
    __syncthreads();
  }

  // ---- epilogue: LDS transpose + coalesced frag-major stores ----
  const int z = nbg >> 10;
  bf16* zdst = (z == 0) ? Qf : (z == 1) ? Kf : Vf;
  const float scale = (z == 0) ? QSCALE : 1.0f;
  const float* bias = (z == 0) ? bq : (z == 1) ? bk : bv;
  const int zoff = nbg & 1023;

  const int bA = mbase / T_;
  const int tA = mbase - bA * T_;
  const int tEndA = (tA + 128 < T_) ? tA + 128 : T_;
  const int tgA0 = tA >> 4;
  const int nA = ((tEndA - 1) >> 4) - tgA0 + 1;
  int nU = nA, tEndB = 0;
  if (tA + 128 > T_ && bA + 1 < B_) {
    tEndB = tA + 128 - T_;
    nU += ((tEndB - 1) >> 4) + 1;
  }

  for (int half = 0; half < 2; half++) {
    if (wc == half) {
#pragma unroll
      for (int i = 0; i < 4; i++)
#pragma unroll
        for (int j = 0; j < 4; j++) {
          int colL = j * 16 + n15;
          float bval = bias[zoff + half * 64 + colL];
#pragma unroll
          for (int r = 0; r < 4; r++) {
            int rowL = wr * 64 + i * 16 + quad * 4 + r;
            smem[rowL * 72 + colL] = (bf16)((acc[i][j][r] + bval) * scale);
          }
        }
    }
    __syncthreads();
    const int h = (zoff >> 6) + half;
    for (int u = w; u < nU; u += 4) {
      int b, tg, tlo, thi;
      if (u < nA) {
        b = bA; tg = tgA0 + u;
        tlo = (tA > tg * 16) ? tA : tg * 16;
        int te = tg * 16 + 16; thi = (te < tEndA) ? te : tEndA;
      } else {
        b = bA + 1; tg = u - nA;
        tlo = tg * 16;
        int te = tg * 16 + 16; thi = (te < tEndB) ? te : tEndB;
      }
      bf16* gb = zdst + (size_t)(b * H_ + h) * FRAG_PER_BH + tg * 1024;
      if (z != 2) {
        int ki = lane & 15, dc = lane >> 4;
        int t = tg * 16 + ki;
        if (t >= tlo && t < thi) {
          int rowL = b * T_ + t - mbase;
          bf16x8 v0 = *reinterpret_cast<const bf16x8*>(smem + rowL * 72 + dc * 8);
          bf16x8 v1 = *reinterpret_cast<const bf16x8*>(smem + rowL * 72 + 32 + dc * 8);
          *reinterpret_cast<bf16x8*>(gb + dc * 128 + ki * 8) = v0;
          *reinterpret_cast<bf16x8*>(gb + 512 + dc * 128 + ki * 8) = v1;
        }
      } else {
        int q2 = (lane >> 4) & 3, d16 = lane & 15;
        int tb = tg * 16 + q2 * 4;
        bool full = (tb >= tlo) && (tb + 3 < thi);
#pragma unroll
        for (int p = 0; p < 2; p++) {
          bf16x8 vv;
#pragma unroll
          for (int dp = 0; dp < 2; dp++)
#pragma unroll
            for (int ki = 0; ki < 4; ki++) {
              int t = tb + ki;
              int rr = (b * T_ + t - mbase) & 127;   // safe for masked elems
              vv[dp * 4 + ki] = smem[rr * 72 + p * 32 + dp * 16 + d16];
            }
          bf16* cp = gb + (p * 4 + q2) * 128 + d16 * 8;
          if (full) {
            *reinterpret_cast<bf16x8*>(cp) = vv;
          } else {
#pragma unroll
            for (int dp = 0; dp < 2; dp++)
#pragma unroll
              for (int ki = 0; ki < 4; ki++) {
                int t = tb + ki;
                if (t >= tlo && t < thi) cp[dp * 4 + ki] = vv[dp * 4 + ki];
              }
          }
        }
      }
    }
    __syncthreads();
  }
}

// ---------------- fused attention (8 waves/block, K+V LDS, online softmax) --
// grid = 512 (one block per bh), 512 threads; wave w handles qt w, w+8, (16).
// Streamed online softmax in GROUPS OF 2 kt: live set ~70 VGPR, well under
// the 128-VGPR cap from 2-blocks/CU LDS occupancy. kt=16 is a masked tail.
__global__ __launch_bounds__(512) void attn_kernel(
    const bf16* __restrict__ Qf, const bf16* __restrict__ Kf,
    const bf16* __restrict__ Vf, bf16* __restrict__ ctx) {
  __shared__ bf16 smem[34816];   // K (17408) then V (17408) = 68 KB

  const int bh = blockIdx.x;
  const int tid = threadIdx.x;
  const int lane = tid & 63, w = tid >> 6;   // w in 0..7
  const int n15 = lane & 15, quad = lane >> 4;
  const int b = bh >> 4, h = bh & 15;

  const bf16* Qb = Qf + (size_t)bh * FRAG_PER_BH;
  const bf16* Kb = Kf + (size_t)bh * FRAG_PER_BH;
  const bf16* Vb = Vf + (size_t)bh * FRAG_PER_BH;

  // stage K and V: 68 chunks of 1KB over 8 waves
  for (int c = w; c < 68; c += 8) {
    const bf16* src = (c < 34) ? (Kb + c * 512) : (Vb + (c - 34) * 512);
    GLD16(src + lane * 8, smem + c * 512);
  }
  __syncthreads();
  const bf16* Ksh = smem;
  const bf16* Vsh = smem + 17408;

  const int fo = quad * 128 + n15 * 8;

#pragma unroll 1
  for (int qt = w; qt < 17; qt += 8) {
    bf16x8 q0 = *reinterpret_cast<const bf16x8*>(Qb + qt * 1024 + fo);
    bf16x8 q1 = *reinterpret_cast<const bf16x8*>(Qb + qt * 1024 + 512 + fo);

    float m = -1e30f, l = 0.f;
    floatx4 o[4] = {};

#pragma unroll 1
    for (int g = 0; g < 8; g++) {
      floatx4 s[2];
#pragma unroll
      for (int j = 0; j < 2; j++) {
        const int kt = g * 2 + j;
        bf16x8 ka0 = *reinterpret_cast<const bf16x8*>(Ksh + kt * 1024 + fo);
        bf16x8 ka1 = *reinterpret_cast<const bf16x8*>(Ksh + kt * 1024 + 512 + fo);
        floatx4 c = {};
        c = __builtin_amdgcn_mfma_f32_16x16x32_bf16(ka0, q0, c, 0, 0, 0);
        c = __builtin_amdgcn_mfma_f32_16x16x32_bf16(ka1, q1, c, 0, 0, 0);
        s[j] = c;
      }
      float gm = -1e30f;
#pragma unroll
      for (int j = 0; j < 2; j++)
#pragma unroll
        for (int r = 0; r < 4; r++) gm = fmaxf(gm, s[j][r]);
      gm = fmaxf(gm, __shfl_xor(gm, 16));
      gm = fmaxf(gm, __shfl_xor(gm, 32));
      const float mnew = fmaxf(m, gm);
      const float alpha = exp2f(m - mnew);
      m = mnew;
      l *= alpha;
      s16x4 pb[2];
#pragma unroll
      for (int j = 0; j < 2; j++) {
        bf16x4 ph;
#pragma unroll
        for (int r = 0; r < 4; r++) {
          float p = exp2f(s[j][r] - mnew);   // scores pre-scaled by log2e/8
          l += p;
          ph[r] = (bf16)p;
        }
        pb[j] = __builtin_bit_cast(s16x4, ph);
      }
#pragma unroll
      for (int dt = 0; dt < 4; dt++) o[dt] = o[dt] * alpha;
#pragma unroll
      for (int j = 0; j < 2; j++) {
        const int kt = g * 2 + j;
#pragma unroll
        for (int p = 0; p < 2; p++) {
          bf16x8 vv = *reinterpret_cast<const bf16x8*>(
              Vsh + ((kt * 2 + p) * 4 + quad) * 128 + n15 * 8);
          s16x8 v16 = __builtin_bit_cast(s16x8, vv);
          s16x4 vlo = __builtin_shufflevector(v16, v16, 0, 1, 2, 3);
          s16x4 vhi = __builtin_shufflevector(v16, v16, 4, 5, 6, 7);
          o[p * 2]     = __builtin_amdgcn_mfma_f32_16x16x16bf16_1k(vlo, pb[j], o[p * 2], 0, 0, 0);
          o[p * 2 + 1] = __builtin_amdgcn_mfma_f32_16x16x16bf16_1k(vhi, pb[j], o[p * 2 + 1], 0, 0, 0);
        }
      }
    }

    // ---- tail: kt = 16 (only key 256 valid: quad 0, r 0) ----
    {
      bf16x8 ka0 = *reinterpret_cast<const bf16x8*>(Ksh + 16 * 1024 + fo);
      bf16x8 ka1 = *reinterpret_cast<const bf16x8*>(Ksh + 16 * 1024 + 512 + fo);
      floatx4 c = {};
      c = __builtin_amdgcn_mfma_f32_16x16x32_bf16(ka0, q0, c, 0, 0, 0);
      c = __builtin_amdgcn_mfma_f32_16x16x32_bf16(ka1, q1, c, 0, 0, 0);
      c[1] = -1e30f; c[2] = -1e30f; c[3] = -1e30f;
      if (quad != 0) c[0] = -1e30f;
      float gm = fmaxf(fmaxf(c[0], c[1]), fmaxf(c[2], c[3]));
      gm = fmaxf(gm, __shfl_xor(gm, 16));
      gm = fmaxf(gm, __shfl_xor(gm, 32));
      const float mnew = fmaxf(m, gm);
      const float alpha = exp2f(m - mnew);
      l *= alpha;
      bf16x4 ph;
#pragma unroll
      for (int r = 0; r < 4; r++) {
        float p = exp2f(c[r] - mnew);
        l += p;
        ph[r] = (bf16)p;
      }
      s16x4 pbt = __builtin_bit_cast(s16x4, ph);
#pragma unroll
      for (int dt = 0; dt < 4; dt++) o[dt] = o[dt] * alpha;
#pragma unroll
      for (int p = 0; p < 2; p++) {
        bf16x8 vv = *reinterpret_cast<const bf16x8*>(
            Vsh + ((16 * 2 + p) * 4 + quad) * 128 + n15 * 8);
        s16x8 v16 = __builtin_bit_cast(s16x8, vv);
        s16x4 vlo = __builtin_shufflevector(v16, v16, 0, 1, 2, 3);
        s16x4 vhi = __builtin_shufflevector(v16, v16, 4, 5, 6, 7);
        o[p * 2]     = __builtin_amdgcn_mfma_f32_16x16x16bf16_1k(vlo, pbt, o[p * 2], 0, 0, 0);
        o[p * 2 + 1] = __builtin_amdgcn_mfma_f32_16x16x16bf16_1k(vhi, pbt, o[p * 2 + 1], 0, 0, 0);
      }
    }

    l += __shfl_xor(l, 16);
    l += __shfl_xor(l, 32);

    int q = qt * 16 + n15;
    if (q < T_) {
      float inv = 1.0f / l;
      size_t ob = ((size_t)(b * T_ + q)) * D_ + h * 64 + quad * 4;
#pragma unroll
      for (int dt = 0; dt < 4; dt++) {
        bf16x4 ov;
#pragma unroll
        for (int r = 0; r < 4; r++) ov[r] = (bf16)(o[dt][r] * inv);
        *reinterpret_cast<bf16x4*>(ctx + ob + dt * 16) = ov;
      }
    }
  }
}

// ---------------- output projection GEMM (R4 128x128, fp32 out) -------------
// grid = 520 = 8 n-tiles (fastest, XCD-resident B) x 65 m-tiles.
__global__ __launch_bounds__(256) void o_gemm(
    const bf16* __restrict__ ctx, const bf16* __restrict__ wo,
    const float* __restrict__ bo, float* __restrict__ out) {
  __shared__ bf16 Ash[128 * 32];
  __shared__ bf16 Bsh[128 * 32];

  const int linear = blockIdx.x;
  const int nbase = (linear & 7) * 128;
  const int mbase = (linear >> 3) * 128;
  const int tid = threadIdx.x;
  const int lane = tid & 63;
  const int w = tid >> 6;
  const int wr = w >> 1, wc = w & 1;
  const int n15 = lane & 15, quad = lane >> 4;

  const int lrow = lane >> 2;
  const int lseg = (lane & 3) * 8;

  floatx4 acc[4][4] = {};

  for (int k0 = 0; k0 < D_; k0 += 32) {
#pragma unroll
    for (int c = 0; c < 2; c++) {
      int r0 = w * 32 + c * 16;
      int row = r0 + lrow;
      int gm = mbase + row; if (gm > NTOK - 1) gm = NTOK - 1;
      GLD16(ctx + (size_t)gm * D_ + k0 + lseg, Ash + r0 * 32);
      GLD16(wo + (size_t)(nbase + row) * D_ + k0 + lseg, Bsh + r0 * 32);
    }
    __syncthreads();
    bf16x8 af[4], bfr[4];
#pragma unroll
    for (int i = 0; i < 4; i++) {
      af[i]  = *reinterpret_cast<const bf16x8*>(Ash + (wr * 64 + i * 16 + n15) * 32 + quad * 8);
      bfr[i] = *reinterpret_cast<const bf16x8*>(Bsh + (wc * 64 + i * 16 + n15) * 32 + quad * 8);
    }
#pragma unroll
    for (int i = 0; i < 4; i++)
#pragma unroll
      for (int j = 0; j < 4; j++)
        acc[i][j] = __builtin_amdgcn_mfma_f32_16x16x32_bf16(af[i], bfr[j], acc[i][j], 0, 0, 0);
    __syncthreads();
  }

#pragma unroll
  for (int i = 0; i < 4; i++) {
    int rowb = mbase + wr * 64 + i * 16 + quad * 4;
#pragma unroll
    for (int j = 0; j < 4; j++) {
      int col = nbase + wc * 64 + j * 16 + n15;
      float bval = bo[col];
#pragma unroll
      for (int r = 0; r < 4; r++) {
        int m = rowb + r;
        if (m < NTOK) out[(size_t)m * D_ + col] = acc[i][j][r] + bval;
      }
    }
  }
}

extern "C" void kernel_launch(void* const* d_in, const int* in_sizes, int n_in,
                              void* d_out, int out_size, void* d_ws, size_t ws_size,
                              hipStream_t stream) {
  const float* hs = (const float*)d_in[0];
  const float* Wq = (const float*)d_in[1];
  const float* bq = (const float*)d_in[2];
  const float* Wk = (const float*)d_in[3];
  const float* bk = (const float*)d_in[4];
  const float* Wv = (const float*)d_in[5];
  const float* bv = (const float*)d_in[6];
  const float* Wo = (const float*)d_in[7];
  const float* bo = (const float*)d_in[8];

  char* ws = (char*)d_ws;
  bf16* xb   = (bf16*)(ws + OFF_XB);
  bf16* wqkv = (bf16*)(ws + OFF_WQKV);
  bf16* wob  = (bf16*)(ws + OFF_WO);
  bf16* Qfw  = (bf16*)(ws + OFF_Q);
  bf16* Kfw  = (bf16*)(ws + OFF_K);
  bf16* Vfw  = (bf16*)(ws + OFF_V);
  bf16* ctx  = (bf16*)(ws + OFF_CTX);

  cast_bf16_kernel<<<2048, 256, 0, stream>>>(hs, xb, NTOK * D_ / 4);
  cast4_kernel<<<dim3(256, 4), 256, 0, stream>>>(
      Wq, Wk, Wv, Wo,
      wqkv, wqkv + (size_t)D_ * D_, wqkv + (size_t)2 * D_ * D_, wob,
      D_ * D_ / 4);

  qkv_gemm<<<1560, 256, 0, stream>>>(xb, wqkv, bq, bk, bv, Qfw, Kfw, Vfw);
  attn_kernel<<<BH_, 512, 0, stream>>>(Qfw, Kfw, Vfw, ctx);
  o_gemm<<<520, 256, 0, stream>>>(ctx, wob, bo, (float*)d_out);
}